// Round 4
// baseline (146.781 us; speedup 1.0000x reference)
//
#include <hip/hip_runtime.h>
#include <math.h>

// LeNet-ish forward, fp32, B=8192.
// conv1+pool folded into a stride-2 6x6 conv with w6 = W1 (*) ones(2,2)/... (x1/4 at use).
// conv1 also emits S1 (2x2 window-sum of its sigmoid output) so conv2 uses the
// S-trick (pool folded into weights) with zero gather cost.
//
// ws: [w6 4KB][w2q 32KB][L2p 64KB][S1: B*1320 f32][h2: B*320 f32]

__device__ __forceinline__ float sigf(float v) {
    return 1.0f / (1.0f + __expf(-v));
}

// --- K0: prep. w6[ky][c][8] from W1; w2q repack; L2 pad 84->88. ---
__global__ void k_prep(const float* __restrict__ W1, const float* __restrict__ W2,
                       const float* __restrict__ L2, float* __restrict__ w6,
                       float* __restrict__ w2q, float* __restrict__ L2p) {
    int i = blockIdx.x * 256 + threadIdx.x;
    if (i < 5000) {
        int kx = i % 5, t = i / 5;
        int ky = t % 5, t2 = t / 5;
        int ic = t2 % 10, c = t2 / 10;
        w2q[((ic * 5 + ky) * 20 + c) * 5 + kx] = W2[i];
    }
    int j = i - 5000;
    if (j >= 0 && j < 10080) L2p[(j / 84) * 88 + (j % 84)] = L2[j];
    int k = i - 15080;
    if (k >= 0 && k < 480) {
        int kx = k % 8, t = k / 8;
        int c = t % 10, ky = t / 10;   // w6 flat index == k with [ky][c][8] layout
        float v = 0.f;
        if (kx < 6) {
            for (int dy = 0; dy < 2; ++dy)
                for (int dx = 0; dx < 2; ++dx) {
                    int sy = ky - dy, sx = kx - dx;
                    if (sy >= 0 && sy < 5 && sx >= 0 && sx < 5)
                        v += W1[c * 25 + sy * 5 + sx];
                }
        }
        w6[k] = v;
    }
}

// --- K1: conv1(6x6 stride2) + sigmoid + window-sum. x[B,1,28,28] -> S1g[B,10,11,12]
// block=512 = 16 groups (im,cg) x 32 lanes (py=l>>1 [12 active], xh=l&1).
// XR f4-tile XOR-swizzled so stride-2-row b128 reads are <=2-way bank aliased.
__global__ __launch_bounds__(512) void k_conv1(
    const float* __restrict__ x, const float* __restrict__ w6g,
    const float* __restrict__ b1, float* __restrict__ S1g) {
    __shared__ float4 XR[8 * 224];   // [im][r*8 + (k ^ ((r>>1)&7))], r<28, k<7
    __shared__ float wq[6][10][8];   // [ky][c][kx pad8]
    __shared__ float bs[10];

    const int tid = threadIdx.x;
    if (tid < 480) ((float*)wq)[tid] = w6g[tid];
    if (tid < 10) bs[tid] = b1[tid];

    const long img0 = (long)blockIdx.x * 8;
    {
        const float4* xg = (const float4*)(x + img0 * 784);
        for (int i = tid; i < 1568; i += 512) {
            int im = i / 196, j = i % 196, r = j / 7, kk = j % 7;
            XR[im * 224 + r * 8 + (kk ^ ((r >> 1) & 7))] = xg[i];
        }
    }
    __syncthreads();

    const int g = tid >> 5, l = tid & 31;
    const int im = g >> 1, cg = g & 1, py = l >> 1, xh = l & 1;

    if (py < 12) {
        float acc[5][6];
#pragma unroll
        for (int a = 0; a < 5; ++a)
#pragma unroll
            for (int b = 0; b < 6; ++b) acc[a][b] = 0.f;

        const float4* xr = &XR[im * 224];
        const int k0 = xh * 3;
#pragma unroll
        for (int ky = 0; ky < 6; ++ky) {
            const int r = 2 * py + ky;
            const int hsh = (r >> 1) & 7;
            const int base = r * 8;
            union { float4 v[4]; float f[16]; } R;
#pragma unroll
            for (int q = 0; q < 4; ++q) R.v[q] = xr[base + ((k0 + q) ^ hsh)];
#pragma unroll
            for (int cc = 0; cc < 5; ++cc) {
                union { float4 v[2]; float f[8]; } W;
                W.v[0] = *(const float4*)&wq[ky][cg * 5 + cc][0];
                W.v[1] = *(const float4*)&wq[ky][cg * 5 + cc][4];
#pragma unroll
                for (int kx = 0; kx < 6; ++kx)
#pragma unroll
                    for (int px = 0; px < 6; ++px)
                        acc[cc][px] += R.f[2 * px + kx] * W.f[kx];
            }
        }

        // sigmoid -> horizontal pair-sum (needs neighbor's first h for xh=0)
        float hh[5][6];
#pragma unroll
        for (int cc = 0; cc < 5; ++cc) {
            float h[6];
#pragma unroll
            for (int px = 0; px < 6; ++px)
                h[px] = sigf(acc[cc][px] * 0.25f + bs[cg * 5 + cc]);
            float nbr = __shfl_down(h[0], 1, 32);  // xh=0 gets xh=1's h[0]
#pragma unroll
            for (int t = 0; t < 5; ++t) hh[cc][t] = h[t] + h[t + 1];
            hh[cc][5] = h[5] + nbr;                // valid for xh=0 only
        }

        // vertical pair-sum from lane l+2 (py+1, same xh), then store
#pragma unroll
        for (int cc = 0; cc < 5; ++cc) {
            float o[6];
#pragma unroll
            for (int t = 0; t < 6; ++t)
                o[t] = hh[cc][t] + __shfl_down(hh[cc][t], 2, 32);
            if (py < 11) {
                float* sp = S1g + ((img0 + im) * 10 + cg * 5 + cc) * 132
                            + py * 12 + xh * 6;
                if (xh == 0) {
                    *(float4*)sp = make_float4(o[0], o[1], o[2], o[3]);
                    *(float2*)(sp + 4) = make_float2(o[4], o[5]);
                } else {  // xx = 6..10 valid, f[11] = pad 0
                    *(float2*)sp = make_float2(o[0], o[1]);
                    *(float2*)(sp + 2) = make_float2(o[2], o[3]);
                    *(float2*)(sp + 4) = make_float2(o[4], 0.f);
                }
            }
        }
    }
}

// --- K2: conv2 + pool + sigmoid. S1g[B,10,11,12] -> h2[B,320] (unchanged) ---
__global__ __launch_bounds__(192) void k_conv2(
    const float* __restrict__ S1g, const float* __restrict__ w2q,
    const float* __restrict__ b2, float* __restrict__ h2) {
    __shared__ float S1t[8][10][132];
    __shared__ float bs[20];

    const int tid = threadIdx.x;
    if (tid < 20) bs[tid] = b2[tid];

    const long img0 = (long)blockIdx.x * 8;
    {
        const float4* sg = (const float4*)(S1g + img0 * 1320);
        float4* sl = (float4*)S1t;
        for (int i = tid; i < 2640; i += 192) sl[i] = sg[i];
    }
    __syncthreads();

    if (tid >= 160) return;
    const int im = tid / 20, r2 = tid % 20, cg = r2 / 4, py = r2 % 4;

    float acc[4][4];
#pragma unroll
    for (int a = 0; a < 4; ++a)
#pragma unroll
        for (int b = 0; b < 4; ++b) acc[a][b] = 0.f;

    for (int ic = 0; ic < 10; ++ic) {
#pragma unroll
        for (int ky = 0; ky < 5; ++ky) {
            union { float4 v[3]; float f[12]; } R;
            const float4* rp = (const float4*)&S1t[im][ic][(2 * py + ky) * 12];
            R.v[0] = rp[0]; R.v[1] = rp[1]; R.v[2] = rp[2];
            union { float4 v[5]; float f[20]; } W;
            const float4* wp = (const float4*)(w2q + (ic * 5 + ky) * 100 + cg * 20);
#pragma unroll
            for (int q = 0; q < 5; ++q) W.v[q] = wp[q];
#pragma unroll
            for (int cc = 0; cc < 4; ++cc)
#pragma unroll
                for (int kx = 0; kx < 5; ++kx) {
                    const float wv = W.f[cc * 5 + kx];
#pragma unroll
                    for (int px = 0; px < 4; ++px)
                        acc[cc][px] += R.f[2 * px + kx] * wv;
                }
        }
    }

    float* outp = h2 + (img0 + im) * 320 + (cg * 4) * 16 + py * 4;
#pragma unroll
    for (int cc = 0; cc < 4; ++cc) {
        union { float4 v; float f[4]; } O;
#pragma unroll
        for (int px = 0; px < 4; ++px)
            O.f[px] = sigf(acc[cc][px] * 0.25f + bs[cg * 4 + cc]);
        *(float4*)(outp + cc * 16) = O.v;
    }
}

// --- K3: FC chain. 8 img/block, 1024 blocks, 256 threads, low VGPR/LDS. ---
// Lane order jg=tid&31 -> per-wave weight loads are one contiguous row chunk.
__global__ __launch_bounds__(256) void k_fc(
    const float* __restrict__ h2, const float* __restrict__ L1,
    const float* __restrict__ Lb1, const float* __restrict__ L2p,
    const float* __restrict__ Lb2, const float* __restrict__ L3,
    const float* __restrict__ Lb3, float* __restrict__ out) {
    __shared__ float h2n[8][324];
    __shared__ float g1n[8][124];
    __shared__ float g2n[8][85];

    const int tid = threadIdx.x;
    const long img0 = (long)blockIdx.x * 8;

    {
        const float4* hg = (const float4*)(h2 + img0 * 320);
        for (int i = tid; i < 640; i += 256) {
            int im = i / 80, off = (i % 80) * 4;
            *(float4*)&h2n[im][off] = hg[i];
        }
    }
    __syncthreads();

    const int jg = tid & 31, im = tid >> 5;

    if (jg < 30) {  // FC1: 320 -> 120
        union { float4 v; float f[4]; } a;
        a.v = *(const float4*)(Lb1 + jg * 4);
#pragma unroll 4
        for (int i = 0; i < 320; ++i) {
            union { float4 v; float f[4]; } w;
            w.v = *(const float4*)(L1 + i * 120 + jg * 4);
            float h = h2n[im][i];
            a.f[0] += w.f[0] * h; a.f[1] += w.f[1] * h;
            a.f[2] += w.f[2] * h; a.f[3] += w.f[3] * h;
        }
#pragma unroll
        for (int q = 0; q < 4; ++q) g1n[im][jg * 4 + q] = sigf(a.f[q]);
    }
    __syncthreads();

    if (jg < 21) {  // FC2: 120 -> 84
        union { float4 v; float f[4]; } a;
        a.v = *(const float4*)(Lb2 + jg * 4);
#pragma unroll 4
        for (int i = 0; i < 120; ++i) {
            union { float4 v; float f[4]; } w;
            w.v = *(const float4*)(L2p + i * 88 + jg * 4);
            float h = g1n[im][i];
            a.f[0] += w.f[0] * h; a.f[1] += w.f[1] * h;
            a.f[2] += w.f[2] * h; a.f[3] += w.f[3] * h;
        }
#pragma unroll
        for (int q = 0; q < 4; ++q) g2n[im][jg * 4 + q] = sigf(a.f[q]);
    }
    __syncthreads();

    if (tid < 128) {  // FC3: 84 -> 10
        const int j = tid & 15, m = tid >> 4;
        if (j < 10) {
            float a = Lb3[j];
#pragma unroll 4
            for (int i = 0; i < 84; ++i) a += g2n[m][i] * L3[i * 10 + j];
            out[(img0 + m) * 10 + j] = a;
        }
    }
}

extern "C" void kernel_launch(void* const* d_in, const int* in_sizes, int n_in,
                              void* d_out, int out_size, void* d_ws, size_t ws_size,
                              hipStream_t stream) {
    const float* x   = (const float*)d_in[0];
    const float* W1  = (const float*)d_in[1];
    const float* b1  = (const float*)d_in[2];
    const float* W2  = (const float*)d_in[3];
    const float* b2  = (const float*)d_in[4];
    const float* L1  = (const float*)d_in[5];
    const float* Lb1 = (const float*)d_in[6];
    const float* L2  = (const float*)d_in[7];
    const float* Lb2 = (const float*)d_in[8];
    const float* L3  = (const float*)d_in[9];
    const float* Lb3 = (const float*)d_in[10];
    float* out = (float*)d_out;

    const int B = in_sizes[0] / 784;  // 8192

    char* ws = (char*)d_ws;
    float* w6  = (float*)ws;                        // 1.9KB (pad 4KB)
    float* w2q = (float*)(ws + 4096);               // 20KB (pad 32KB)
    float* L2p = (float*)(ws + 4096 + 32768);       // 42.2KB (pad 64KB)
    float* S1g = (float*)(ws + 4096 + 32768 + 65536);
    float* h2  = (float*)(ws + 4096 + 32768 + 65536 + (size_t)B * 1320 * 4);

    hipLaunchKernelGGL(k_prep, dim3(61), dim3(256), 0, stream, W1, W2, L2, w6, w2q, L2p);
    hipLaunchKernelGGL(k_conv1, dim3(B / 8), dim3(512), 0, stream, x, w6, b1, S1g);
    hipLaunchKernelGGL(k_conv2, dim3(B / 8), dim3(192), 0, stream, S1g, w2q, b2, h2);
    hipLaunchKernelGGL(k_fc, dim3(B / 8), dim3(256), 0, stream,
                       h2, L1, Lb1, L2p, Lb2, L3, Lb3, out);
}

// Round 6
// 135.682 us; speedup vs baseline: 1.0818x; 1.0818x over previous
//
#include <hip/hip_runtime.h>
#include <math.h>

// LeNet-ish forward, fp32, B=8192.
// conv1+pool folded into stride-2 6x6 conv (w6 = W1 (*) ones(2,2), /4 at use).
// conv1 emits S1 (2x2 window-sum of its sigmoid output) straight into LDS;
// conv2 (S-trick) consumes it in the same kernel. h1/S1 never touch HBM.
// FC: 32 img/block, 4-out x 4-img register tiles -> 16 FMA per weight load.
//
// ws: [w6 4KB][w2q 32KB][L2p 64KB][h2: B*320 f32]

__device__ __forceinline__ float sigf(float v) {
    return 1.0f / (1.0f + __expf(-v));
}

// --- K0: prep. w6[ky][c][8] from W1; w2q repack; L2 pad 84->88. ---
__global__ void k_prep(const float* __restrict__ W1, const float* __restrict__ W2,
                       const float* __restrict__ L2, float* __restrict__ w6,
                       float* __restrict__ w2q, float* __restrict__ L2p) {
    int i = blockIdx.x * 256 + threadIdx.x;
    if (i < 5000) {
        int kx = i % 5, t = i / 5;
        int ky = t % 5, t2 = t / 5;
        int ic = t2 % 10, c = t2 / 10;
        w2q[((ic * 5 + ky) * 20 + c) * 5 + kx] = W2[i];
    }
    int j = i - 5000;
    if (j >= 0 && j < 10080) L2p[(j / 84) * 88 + (j % 84)] = L2[j];
    int k = i - 15080;
    if (k >= 0 && k < 480) {
        int kx = k % 8, t = k / 8;
        int c = t % 10, ky = t / 10;
        float v = 0.f;
        if (kx < 6) {
            for (int dy = 0; dy < 2; ++dy)
                for (int dx = 0; dx < 2; ++dx) {
                    int sy = ky - dy, sx = kx - dx;
                    if (sy >= 0 && sy < 5 && sx >= 0 && sx < 5)
                        v += W1[c * 25 + sy * 5 + sx];
                }
        }
        w6[k] = v;
    }
}

// --- K1: fused conv1+pool+sig -> S1(LDS) -> conv2+pool+sig -> h2[B,320]
// 8 images/block, 256 threads.
// Phase B: 8 groups of 32 lanes (im); lane = (py=l>>1 [12 active], xh=l&1);
//          each thread: all 10 channels x 6 px, x read direct from global.
// Phase C: 160 threads = (im8, cg5, py4), acc[4oc][4px], weights from LDS.
#define S1STR 1348  // per-image float stride; 1348%32==4 -> images bank-staggered
__global__ __launch_bounds__(256) void k_convs(
    const float* __restrict__ x, const float* __restrict__ w6g,
    const float* __restrict__ b1, const float* __restrict__ w2qg,
    const float* __restrict__ b2, float* __restrict__ h2) {
    __shared__ float S1t[8 * S1STR];   // 43.1 KB
    __shared__ float wq1[6][10][8];    // 1.9 KB
    __shared__ float w2s[5000];        // 20 KB  (FIX r5: was 2000 -> OOB reads for ic>=4)
    __shared__ float bs1[10];
    __shared__ float bs2[20];

    const int tid = threadIdx.x;
    for (int i = tid; i < 480; i += 256) ((float*)wq1)[i] = w6g[i];
    for (int i = tid; i < 5000; i += 256) w2s[i] = w2qg[i];
    if (tid < 10) bs1[tid] = b1[tid];
    if (tid < 20) bs2[tid] = b2[tid];
    __syncthreads();

    const long img0 = (long)blockIdx.x * 8;

    // ---- phase B: conv1 ----
    {
        const int im = tid >> 5, l = tid & 31, py = l >> 1, xh = l & 1;
        if (py < 12) {
            float acc[10][6];
#pragma unroll
            for (int a = 0; a < 10; ++a)
#pragma unroll
                for (int b = 0; b < 6; ++b) acc[a][b] = 0.f;

            const float* xim = x + (img0 + im) * 784 + xh * 12;
#pragma unroll
            for (int ky = 0; ky < 6; ++ky) {
                const int r = 2 * py + ky;
                union { float4 v[4]; float f[16]; } R;
                const float4* rp = (const float4*)(xim + r * 28);
#pragma unroll
                for (int q = 0; q < 4; ++q) R.v[q] = rp[q];
#pragma unroll
                for (int cc = 0; cc < 10; ++cc) {
                    union { float4 v[2]; float f[8]; } W;
                    W.v[0] = *(const float4*)&wq1[ky][cc][0];
                    W.v[1] = *(const float4*)&wq1[ky][cc][4];
#pragma unroll
                    for (int kx = 0; kx < 6; ++kx)
#pragma unroll
                        for (int px = 0; px < 6; ++px)
                            acc[cc][px] += R.f[2 * px + kx] * W.f[kx];
                }
            }

#pragma unroll
            for (int cc = 0; cc < 10; ++cc) {
                float h[6];
#pragma unroll
                for (int px = 0; px < 6; ++px)
                    h[px] = sigf(acc[cc][px] * 0.25f + bs1[cc]);
                float nbr = __shfl_down(h[0], 1, 32);  // xh=0 gets xh=1's h[0]
                float hh[6];
#pragma unroll
                for (int t = 0; t < 5; ++t) hh[t] = h[t] + h[t + 1];
                hh[5] = h[5] + nbr;  // valid for xh=0 only
                float o[6];
#pragma unroll
                for (int t = 0; t < 6; ++t)
                    o[t] = hh[t] + __shfl_down(hh[t], 2, 32);  // py+1, same xh
                if (py < 11) {
                    float* sp = S1t + im * S1STR + cc * 132 + py * 12 + xh * 6;
                    if (xh == 0) {
                        *(float4*)sp = make_float4(o[0], o[1], o[2], o[3]);
                        *(float2*)(sp + 4) = make_float2(o[4], o[5]);
                    } else {  // col 11 of S1 is pad = 0
                        *(float2*)sp = make_float2(o[0], o[1]);
                        *(float2*)(sp + 2) = make_float2(o[2], o[3]);
                        *(float2*)(sp + 4) = make_float2(o[4], 0.f);
                    }
                }
            }
        }
    }
    __syncthreads();

    // ---- phase C: conv2 ----
    if (tid < 160) {
        const int im = tid / 20, r2 = tid % 20, cg = r2 / 4, py = r2 % 4;
        float acc[4][4];
#pragma unroll
        for (int a = 0; a < 4; ++a)
#pragma unroll
            for (int b = 0; b < 4; ++b) acc[a][b] = 0.f;

        const float* s1 = S1t + im * S1STR;
        for (int ic = 0; ic < 10; ++ic) {
#pragma unroll
            for (int ky = 0; ky < 5; ++ky) {
                union { float4 v[3]; float f[12]; } R;
                const float4* rp = (const float4*)(s1 + ic * 132 + (2 * py + ky) * 12);
                R.v[0] = rp[0]; R.v[1] = rp[1]; R.v[2] = rp[2];
                union { float4 v[5]; float f[20]; } W;
                const float4* wp = (const float4*)(w2s + (ic * 5 + ky) * 100 + cg * 20);
#pragma unroll
                for (int q = 0; q < 5; ++q) W.v[q] = wp[q];
#pragma unroll
                for (int cc = 0; cc < 4; ++cc)
#pragma unroll
                    for (int kx = 0; kx < 5; ++kx) {
                        const float wv = W.f[cc * 5 + kx];
#pragma unroll
                        for (int px = 0; px < 4; ++px)
                            acc[cc][px] += R.f[2 * px + kx] * wv;
                    }
            }
        }

        float* outp = h2 + (img0 + im) * 320 + (cg * 4) * 16 + py * 4;
#pragma unroll
        for (int cc = 0; cc < 4; ++cc) {
            union { float4 v; float f[4]; } O;
#pragma unroll
            for (int px = 0; px < 4; ++px)
                O.f[px] = sigf(acc[cc][px] * 0.25f + bs2[cg * 4 + cc]);
            *(float4*)(outp + cc * 16) = O.v;
        }
    }
}

// --- K2: FC chain. 32 img/block (grid 256), wave w owns images 4w..4w+3. ---
// Thread (w, jg): 4 outputs x 4 images -> 16 FMA per f4 weight load.
// Activation LDS reads are wave-broadcast (all lanes same address).
__global__ __launch_bounds__(256) void k_fc(
    const float* __restrict__ h2, const float* __restrict__ L1,
    const float* __restrict__ Lb1, const float* __restrict__ L2p,
    const float* __restrict__ Lb2, const float* __restrict__ L3,
    const float* __restrict__ Lb3, float* __restrict__ out) {
    __shared__ float h2n[32][324];  // 41.5 KB
    __shared__ float g1n[32][124];  // 15.9 KB
    __shared__ float g2n[32][85];   // 10.9 KB

    const int tid = threadIdx.x;
    const long img0 = (long)blockIdx.x * 32;

    {
        const float4* hg = (const float4*)(h2 + img0 * 320);
        for (int i = tid; i < 2560; i += 256) {
            int im = i / 80, off = (i % 80) * 4;
            *(float4*)&h2n[im][off] = hg[i];
        }
    }
    __syncthreads();

    const int w = tid >> 5, jg = tid & 31, i0 = w * 4;

    if (jg < 30) {  // FC1: 320 -> 120
        union { float4 v; float f[4]; } bv;
        bv.v = *(const float4*)(Lb1 + jg * 4);
        float acc[4][4];
#pragma unroll
        for (int q = 0; q < 4; ++q)
#pragma unroll
            for (int p = 0; p < 4; ++p) acc[q][p] = bv.f[q];
#pragma unroll 4
        for (int i = 0; i < 320; ++i) {
            union { float4 v; float f[4]; } wv;
            wv.v = *(const float4*)(L1 + i * 120 + jg * 4);
            float h0 = h2n[i0 + 0][i], h1 = h2n[i0 + 1][i];
            float h2v = h2n[i0 + 2][i], h3 = h2n[i0 + 3][i];
#pragma unroll
            for (int q = 0; q < 4; ++q) {
                acc[q][0] += wv.f[q] * h0; acc[q][1] += wv.f[q] * h1;
                acc[q][2] += wv.f[q] * h2v; acc[q][3] += wv.f[q] * h3;
            }
        }
#pragma unroll
        for (int q = 0; q < 4; ++q)
#pragma unroll
            for (int p = 0; p < 4; ++p)
                g1n[i0 + p][jg * 4 + q] = sigf(acc[q][p]);
    }
    __syncthreads();

    if (jg < 21) {  // FC2: 120 -> 84
        union { float4 v; float f[4]; } bv;
        bv.v = *(const float4*)(Lb2 + jg * 4);
        float acc[4][4];
#pragma unroll
        for (int q = 0; q < 4; ++q)
#pragma unroll
            for (int p = 0; p < 4; ++p) acc[q][p] = bv.f[q];
#pragma unroll 4
        for (int i = 0; i < 120; ++i) {
            union { float4 v; float f[4]; } wv;
            wv.v = *(const float4*)(L2p + i * 88 + jg * 4);
            float h0 = g1n[i0 + 0][i], h1 = g1n[i0 + 1][i];
            float h2v = g1n[i0 + 2][i], h3 = g1n[i0 + 3][i];
#pragma unroll
            for (int q = 0; q < 4; ++q) {
                acc[q][0] += wv.f[q] * h0; acc[q][1] += wv.f[q] * h1;
                acc[q][2] += wv.f[q] * h2v; acc[q][3] += wv.f[q] * h3;
            }
        }
#pragma unroll
        for (int q = 0; q < 4; ++q)
#pragma unroll
            for (int p = 0; p < 4; ++p)
                g2n[i0 + p][jg * 4 + q] = sigf(acc[q][p]);
    }
    __syncthreads();

    for (int idx = tid; idx < 320; idx += 256) {  // FC3: 84 -> 10
        const int j = idx % 10, m = idx / 10;
        float a = Lb3[j];
#pragma unroll 4
        for (int i = 0; i < 84; ++i) a += g2n[m][i] * L3[i * 10 + j];
        out[(img0 + m) * 10 + j] = a;
    }
}

extern "C" void kernel_launch(void* const* d_in, const int* in_sizes, int n_in,
                              void* d_out, int out_size, void* d_ws, size_t ws_size,
                              hipStream_t stream) {
    const float* x   = (const float*)d_in[0];
    const float* W1  = (const float*)d_in[1];
    const float* b1  = (const float*)d_in[2];
    const float* W2  = (const float*)d_in[3];
    const float* b2  = (const float*)d_in[4];
    const float* L1  = (const float*)d_in[5];
    const float* Lb1 = (const float*)d_in[6];
    const float* L2  = (const float*)d_in[7];
    const float* Lb2 = (const float*)d_in[8];
    const float* L3  = (const float*)d_in[9];
    const float* Lb3 = (const float*)d_in[10];
    float* out = (float*)d_out;

    const int B = in_sizes[0] / 784;  // 8192

    char* ws = (char*)d_ws;
    float* w6  = (float*)ws;                        // 1.9KB (pad 4KB)
    float* w2q = (float*)(ws + 4096);               // 20KB (pad 32KB)
    float* L2p = (float*)(ws + 4096 + 32768);       // 42.2KB (pad 64KB)
    float* h2  = (float*)(ws + 4096 + 32768 + 65536);

    hipLaunchKernelGGL(k_prep, dim3(61), dim3(256), 0, stream, W1, W2, L2, w6, w2q, L2p);
    hipLaunchKernelGGL(k_convs, dim3(B / 8), dim3(256), 0, stream, x, w6, b1, w2q, b2, h2);
    hipLaunchKernelGGL(k_fc, dim3(B / 32), dim3(256), 0, stream,
                       h2, L1, Lb1, L2p, Lb2, L3, Lb3, out);
}